// Round 2
// baseline (266.977 us; speedup 1.0000x reference)
//
#include <hip/hip_runtime.h>
#include <hip/hip_bf16.h>

// ---------- types / helpers ----------
typedef __attribute__((ext_vector_type(8))) short bh8;   // 8 bf16 bit patterns (4 VGPRs)
typedef __attribute__((ext_vector_type(4))) float fx4;

#define GLOAD16(g, l)                                                          \
  __builtin_amdgcn_global_load_lds(                                            \
      (const __attribute__((address_space(1))) void*)(g),                      \
      (__attribute__((address_space(3))) void*)(l), 16, 0, 0)

__device__ __forceinline__ unsigned short f2bf(float f) {
  unsigned int u = __float_as_uint(f);
  u += 0x7fffu + ((u >> 16) & 1u);     // RNE
  return (unsigned short)(u >> 16);
}
__device__ __forceinline__ float bf2f(short h) {
  return __uint_as_float(((unsigned int)(unsigned short)h) << 16);
}

// ---------- kernel 1: transpose + f32->bf16 convert ----------
// in: (Bn, R, C) f32 ; out: (Bn, C, R) bf16-bits
__global__ __launch_bounds__(256) void transpose_cvt(
    const float* __restrict__ in, short* __restrict__ out, int R, int Ccols) {
  __shared__ float tile[64][65];
  const int b = blockIdx.z;
  const int c0 = blockIdx.x * 64;
  const int r0 = blockIdx.y * 64;
  const float* ip = in + (size_t)b * R * Ccols;
  short* op = out + (size_t)b * Ccols * R;
  const int tx = threadIdx.x & 63, ty = threadIdx.x >> 6;
#pragma unroll
  for (int i = 0; i < 16; ++i) {
    int r = ty + i * 4;
    tile[tx][r] = ip[(size_t)(r0 + r) * Ccols + c0 + tx];
  }
  __syncthreads();
#pragma unroll
  for (int i = 0; i < 16; ++i) {
    int cc = ty + i * 4;  // local col -> output row
    op[(size_t)(c0 + cc) * R + r0 + tx] = (short)f2bf(tile[cc][tx]);
  }
}

// ---------- GEMM: C = A(MxK) * Bt(NxK)^T, bf16 in, fp32 accum ----------
// MODE 1: out bf16 row-major MxN, bias indexed by col (b_in)
// MODE 2: rows are channels (M=512), cols are tokens (global tok = tok0+n);
//         out fp32 written to (B=8, C=512, S=4096), bias indexed by row (b_out)
template <int MODE>
__global__ __launch_bounds__(256) void gemm_bt(
    const short* __restrict__ A, const short* __restrict__ Bt,
    const float* __restrict__ bias, void* __restrict__ Cout,
    int M, int N, int K, int tok0) {
  __shared__ short As[128 * 32] __attribute__((aligned(16)));
  __shared__ short Bs[128 * 32] __attribute__((aligned(16)));
  const int tid = threadIdx.x;
  const int lane = tid & 63;
  const int wv = tid >> 6;
  const int wr = wv >> 1, wc = wv & 1;
  const int m0 = blockIdx.y * 128, n0 = blockIdx.x * 128;

  const int lr = lane & 15;
  const int lk = (lane >> 4) * 8;

  fx4 acc[4][4] = {};

  const int srow = tid >> 2;           // 0..63
  const int skoff = (tid & 3) * 8;     // 0,8,16,24
  const size_t abase = (size_t)(m0 + srow) * K + skoff;
  const size_t bbase = (size_t)(n0 + srow) * K + skoff;
  char* lA0 = (char*)As + wv * 1024;
  char* lA1 = (char*)As + 4096 + wv * 1024;
  char* lB0 = (char*)Bs + wv * 1024;
  char* lB1 = (char*)Bs + 4096 + wv * 1024;

  for (int k0 = 0; k0 < K; k0 += 32) {
    if (k0) __syncthreads();
    GLOAD16(A + abase + k0, lA0);
    GLOAD16(A + abase + (size_t)64 * K + k0, lA1);
    GLOAD16(Bt + bbase + k0, lB0);
    GLOAD16(Bt + bbase + (size_t)64 * K + k0, lB1);
    __syncthreads();

    bh8 af[4], bfm[4];
#pragma unroll
    for (int i = 0; i < 4; ++i) {
      af[i] = *(const bh8*)&As[(wr * 64 + i * 16 + lr) * 32 + lk];
      bfm[i] = *(const bh8*)&Bs[(wc * 64 + i * 16 + lr) * 32 + lk];
    }
#pragma unroll
    for (int i = 0; i < 4; ++i)
#pragma unroll
      for (int j = 0; j < 4; ++j)
        acc[i][j] = __builtin_amdgcn_mfma_f32_16x16x32_bf16(af[i], bfm[j],
                                                            acc[i][j], 0, 0, 0);
  }

  if (MODE == 1) {
    short* C = (short*)Cout;
#pragma unroll
    for (int i = 0; i < 4; ++i) {
      const int gm = m0 + wr * 64 + i * 16 + (lane >> 4) * 4;
#pragma unroll
      for (int j = 0; j < 4; ++j) {
        const int gn = n0 + wc * 64 + j * 16 + lr;
        const float bv = bias[gn];
#pragma unroll
        for (int r = 0; r < 4; ++r)
          C[(size_t)(gm + r) * N + gn] = (short)f2bf(acc[i][j][r] + bv);
      }
    }
  } else {
    float* C = (float*)Cout;
#pragma unroll
    for (int i = 0; i < 4; ++i) {
      const int ch0 = m0 + wr * 64 + i * 16 + (lane >> 4) * 4;
#pragma unroll
      for (int j = 0; j < 4; ++j) {
        const int t = tok0 + n0 + wc * 64 + j * 16 + lr;
        const int bb = t >> 12, s = t & 4095;
#pragma unroll
        for (int r = 0; r < 4; ++r) {
          const int ch = ch0 + r;
          C[((size_t)(bb * 512 + ch)) * 4096 + s] = acc[i][j][r] + bias[ch];
        }
      }
    }
  }
}

// ---------- attention over heads axis: one wave per token ----------
// QKV: (Mc, 1536) bf16 ; per token, per head h: q=row[h*192..+64), k=+64, v=+128
// AO: (Mc, 512) bf16 (chunk-local rows, caller offsets the pointer)
__global__ __launch_bounds__(256) void attn_kernel(
    const short* __restrict__ QKV, short* __restrict__ AO) {
  __shared__ short sq[4][1536] __attribute__((aligned(16)));
  const int tid = threadIdx.x, lane = tid & 63, wv = tid >> 6;
  const int t = blockIdx.x * 4 + wv;

  {  // stage 1536 bf16 (3072 B) per wave: 3 x (64 lanes x 16 B)
    const short* g = QKV + (size_t)t * 1536 + lane * 8;
    char* l = (char*)&sq[wv][0];
    GLOAD16(g, l);
    GLOAD16(g + 512, l + 1024);
    GLOAD16(g + 1024, l + 2048);
  }
  asm volatile("s_waitcnt vmcnt(0)" ::: "memory");

  const int i = lane >> 3, j = lane & 7;
  const short* q = &sq[wv][i * 192];
  const short* k = &sq[wv][j * 192 + 64];
  float s = 0.f;
#pragma unroll
  for (int c = 0; c < 8; ++c) {
    bh8 qa = *(const bh8*)&q[c * 8];
    bh8 ka = *(const bh8*)&k[c * 8];
#pragma unroll
    for (int e = 0; e < 8; ++e) s += bf2f(qa[e]) * bf2f(ka[e]);
  }
  s *= 0.125f;  // HEAD_DIM^-0.5

  float m = s;
  m = fmaxf(m, __shfl_xor(m, 1));
  m = fmaxf(m, __shfl_xor(m, 2));
  m = fmaxf(m, __shfl_xor(m, 4));
  float p = __expf(s - m);
  float sum = p;
  sum += __shfl_xor(sum, 1);
  sum += __shfl_xor(sum, 2);
  sum += __shfl_xor(sum, 4);
  const float a = p / sum;

  // output: lane covers head i, dims d = j*8 .. j*8+7
  float o[8] = {};
#pragma unroll
  for (int jj = 0; jj < 8; ++jj) {
    const float aj = __shfl(a, (lane & 56) | jj);
    bh8 va = *(const bh8*)&sq[wv][jj * 192 + 128 + j * 8];
#pragma unroll
    for (int e = 0; e < 8; ++e) o[e] += aj * bf2f(va[e]);
  }
  bh8 ov;
#pragma unroll
  for (int e = 0; e < 8; ++e) ov[e] = (short)f2bf(o[e]);
  *(bh8*)&AO[(size_t)t * 512 + i * 64 + j * 8] = ov;
}

// ---------- launch ----------
extern "C" void kernel_launch(void* const* d_in, const int* in_sizes, int n_in,
                              void* d_out, int out_size, void* d_ws,
                              size_t ws_size, hipStream_t stream) {
  const float* x = (const float*)d_in[0];
  // d_in[1] = _h (unused)
  const float* W_in = (const float*)d_in[2];
  const float* b_in = (const float*)d_in[3];
  const float* W_out = (const float*)d_in[4];
  const float* b_out = (const float*)d_in[5];
  float* out = (float*)d_out;

  // ws carve-up (bf16-bit buffers):
  //   Xbf  : 32768 x 512   (token-major X; later re-used per-chunk as AO)
  //   WinT : 1536 x 512
  //   WoutT:  512 x 512
  //   QKVc : (32768/NC) x 1536  (per-chunk QKV)
  // NC adapts to ws_size: peak = 34 MB + 96/NC MB (NC=1: 130 MB, 4: 58 MB).
  short* Xbf = (short*)d_ws;
  short* WinT = Xbf + (size_t)32768 * 512;
  short* WoutT = WinT + (size_t)1536 * 512;
  short* QKVc = WoutT + (size_t)512 * 512;

  const size_t fixed_bytes =
      ((size_t)32768 * 512 + (size_t)1536 * 512 + (size_t)512 * 512) * 2;
  int NC = 1;
  while (NC < 256 &&
         fixed_bytes + ((size_t)32768 / NC) * 1536 * 2 > ws_size)
    NC <<= 1;
  const int Mc = 32768 / NC;

  // X: (8,512,4096) -> (32768,512) bf16
  transpose_cvt<<<dim3(64, 8, 8), 256, 0, stream>>>(x, Xbf, 512, 4096);
  // W_in: (512,1536) -> (1536,512) bf16
  transpose_cvt<<<dim3(24, 8, 1), 256, 0, stream>>>(W_in, WinT, 512, 1536);
  // W_out: (512,512) -> (512,512)^T bf16
  transpose_cvt<<<dim3(8, 8, 1), 256, 0, stream>>>(W_out, WoutT, 512, 512);

  for (int c = 0; c < NC; ++c) {
    const int t0 = c * Mc;
    short* Ach = Xbf + (size_t)t0 * 512;  // chunk's X rows; later its AO rows
    // GEMM1: QKVc = Ach @ WinT^T + b_in   (M=Mc, N=1536, K=512)
    gemm_bt<1><<<dim3(12, Mc / 128), 256, 0, stream>>>(Ach, WinT, b_in, QKVc,
                                                       Mc, 1536, 512, 0);
    // attention over heads; AO written in-place over the chunk's X rows
    attn_kernel<<<dim3(Mc / 4), 256, 0, stream>>>(QKVc, Ach);
    // GEMM2: out(ch, tok0+n) = WoutT @ AO^T + b_out, scattered to (B,C,S) f32
    gemm_bt<2><<<dim3(Mc / 128, 4), 256, 0, stream>>>(WoutT, Ach, b_out, out,
                                                      512, Mc, 512, t0);
  }
}

// Round 3
// 255.771 us; speedup vs baseline: 1.0438x; 1.0438x over previous
//
#include <hip/hip_runtime.h>
#include <hip/hip_bf16.h>

// ---------- types / helpers ----------
typedef __attribute__((ext_vector_type(8))) short bh8;   // 8 bf16 bit patterns (4 VGPRs)
typedef __attribute__((ext_vector_type(4))) float fx4;

#define GLOAD16(g, l)                                                          \
  __builtin_amdgcn_global_load_lds(                                            \
      (const __attribute__((address_space(1))) void*)(g),                      \
      (__attribute__((address_space(3))) void*)(l), 16, 0, 0)

__device__ __forceinline__ unsigned short f2bf(float f) {
  unsigned int u = __float_as_uint(f);
  u += 0x7fffu + ((u >> 16) & 1u);     // RNE
  return (unsigned short)(u >> 16);
}
__device__ __forceinline__ float bf2f(short h) {
  return __uint_as_float(((unsigned int)(unsigned short)h) << 16);
}

// ---------- kernel 1: transpose + f32->bf16 convert ----------
// in: (Bn, R, C) f32 ; out: (Bn, C, R) bf16-bits
__global__ __launch_bounds__(256) void transpose_cvt(
    const float* __restrict__ in, short* __restrict__ out, int R, int Ccols) {
  __shared__ float tile[64][65];
  const int b = blockIdx.z;
  const int c0 = blockIdx.x * 64;
  const int r0 = blockIdx.y * 64;
  const float* ip = in + (size_t)b * R * Ccols;
  short* op = out + (size_t)b * Ccols * R;
  const int tx = threadIdx.x & 63, ty = threadIdx.x >> 6;
#pragma unroll
  for (int i = 0; i < 16; ++i) {
    int r = ty + i * 4;
    tile[tx][r] = ip[(size_t)(r0 + r) * Ccols + c0 + tx];
  }
  __syncthreads();
#pragma unroll
  for (int i = 0; i < 16; ++i) {
    int cc = ty + i * 4;  // local col -> output row
    op[(size_t)(c0 + cc) * R + r0 + tx] = (short)f2bf(tile[cc][tx]);
  }
}

// ---------- GEMM: C = A(MxK) * Bt(NxK)^T, bf16 in, fp32 accum ----------
// 2-phase pipeline: double-buffered LDS, prefetch next K-tile issued BEFORE
// current tile's ds_read+MFMA; one vmcnt-drain+barrier per iter (T3/T4 min).
// XCD-aware block swizzle (T1): same-A-panel (MODE1) / same-B-panel (MODE2)
// blocks land on one XCD so panel re-reads hit that XCD's L2.
// MODE 1: out bf16 row-major MxN, bias indexed by col (b_in)
// MODE 2: rows are channels (M=512), cols are tokens (global tok = tok0+n);
//         out fp32 written to (B=8, C=512, S=4096), bias indexed by row (b_out)
template <int MODE>
__global__ __launch_bounds__(256) void gemm_bt(
    const short* __restrict__ A, const short* __restrict__ Bt,
    const float* __restrict__ bias, void* __restrict__ Cout,
    int M, int N, int K, int tok0) {
  __shared__ short As[2][128 * 32] __attribute__((aligned(16)));
  __shared__ short Bs[2][128 * 32] __attribute__((aligned(16)));
  const int tid = threadIdx.x;
  const int lane = tid & 63;
  const int wv = tid >> 6;
  const int wr = wv >> 1, wc = wv & 1;

  // ---- XCD-aware swizzle (bijective: nwg % 8 == 0 for all our grids) ----
  const int nbx = gridDim.x, nby = gridDim.y;
  const int nwg = nbx * nby;
  int h = blockIdx.y * nbx + blockIdx.x;
  int L = h;
  if ((nwg & 7) == 0) {
    const int q = nwg >> 3;
    L = (h & 7) * q + (h >> 3);
  }
  int bx, by;
  if (MODE == 1) {  // x-fastest: consecutive L share by (A panel)
    by = L / nbx;
    bx = L - by * nbx;
  } else {          // y-fastest: consecutive L share bx (B panel)
    bx = L / nby;
    by = L - bx * nby;
  }
  const int m0 = by * 128, n0 = bx * 128;

  const int lr = lane & 15;
  const int lk = (lane >> 4) * 8;

  fx4 acc[4][4] = {};

  const int srow = tid >> 2;           // 0..63
  const int skoff = (tid & 3) * 8;     // 0,8,16,24
  const size_t abase = (size_t)(m0 + srow) * K + skoff;
  const size_t bbase = (size_t)(n0 + srow) * K + skoff;
  const int ldoff = wv * 1024;         // per-wave LDS dest byte offset

  // prologue: stage K-tile 0 into buf 0
  {
    char* lA = (char*)As[0] + ldoff;
    char* lB = (char*)Bs[0] + ldoff;
    GLOAD16(A + abase, lA);
    GLOAD16(A + abase + (size_t)64 * K, lA + 4096);
    GLOAD16(Bt + bbase, lB);
    GLOAD16(Bt + bbase + (size_t)64 * K, lB + 4096);
  }
  __syncthreads();  // drains vmcnt(0) + barrier

  int cur = 0;
  for (int k0 = 0; k0 < K; k0 += 32) {
    // issue NEXT tile's loads first (latency hides under ds_read+MFMA below)
    if (k0 + 32 < K) {
      char* lA = (char*)As[cur ^ 1] + ldoff;
      char* lB = (char*)Bs[cur ^ 1] + ldoff;
      GLOAD16(A + abase + k0 + 32, lA);
      GLOAD16(A + abase + (size_t)64 * K + k0 + 32, lA + 4096);
      GLOAD16(Bt + bbase + k0 + 32, lB);
      GLOAD16(Bt + bbase + (size_t)64 * K + k0 + 32, lB + 4096);
    }

    bh8 af[4], bfm[4];
#pragma unroll
    for (int i = 0; i < 4; ++i) {
      af[i] = *(const bh8*)&As[cur][(wr * 64 + i * 16 + lr) * 32 + lk];
      bfm[i] = *(const bh8*)&Bs[cur][(wc * 64 + i * 16 + lr) * 32 + lk];
    }
#pragma unroll
    for (int i = 0; i < 4; ++i)
#pragma unroll
      for (int j = 0; j < 4; ++j)
        acc[i][j] = __builtin_amdgcn_mfma_f32_16x16x32_bf16(af[i], bfm[j],
                                                            acc[i][j], 0, 0, 0);

    __syncthreads();  // vmcnt(0): prefetched tile landed; lgkm drained; flip
    cur ^= 1;
  }

  if (MODE == 1) {
    short* C = (short*)Cout;
#pragma unroll
    for (int i = 0; i < 4; ++i) {
      const int gm = m0 + wr * 64 + i * 16 + (lane >> 4) * 4;
#pragma unroll
      for (int j = 0; j < 4; ++j) {
        const int gn = n0 + wc * 64 + j * 16 + lr;
        const float bv = bias[gn];
#pragma unroll
        for (int r = 0; r < 4; ++r)
          C[(size_t)(gm + r) * N + gn] = (short)f2bf(acc[i][j][r] + bv);
      }
    }
  } else {
    float* C = (float*)Cout;
#pragma unroll
    for (int i = 0; i < 4; ++i) {
      const int ch0 = m0 + wr * 64 + i * 16 + (lane >> 4) * 4;
#pragma unroll
      for (int j = 0; j < 4; ++j) {
        const int t = tok0 + n0 + wc * 64 + j * 16 + lr;
        const int bb = t >> 12, s = t & 4095;
#pragma unroll
        for (int r = 0; r < 4; ++r) {
          const int ch = ch0 + r;
          C[((size_t)(bb * 512 + ch)) * 4096 + s] = acc[i][j][r] + bias[ch];
        }
      }
    }
  }
}

// ---------- attention over heads axis: one wave per token ----------
// QKV: (Mc, 1536) bf16 ; per token, per head h: q=row[h*192..+64), k=+64, v=+128
// AO: (Mc, 512) bf16 (chunk-local rows, caller offsets the pointer)
__global__ __launch_bounds__(256) void attn_kernel(
    const short* __restrict__ QKV, short* __restrict__ AO) {
  __shared__ short sq[4][1536] __attribute__((aligned(16)));
  const int tid = threadIdx.x, lane = tid & 63, wv = tid >> 6;
  const int t = blockIdx.x * 4 + wv;

  {  // stage 1536 bf16 (3072 B) per wave: 3 x (64 lanes x 16 B)
    const short* g = QKV + (size_t)t * 1536 + lane * 8;
    char* l = (char*)&sq[wv][0];
    GLOAD16(g, l);
    GLOAD16(g + 512, l + 1024);
    GLOAD16(g + 1024, l + 2048);
  }
  asm volatile("s_waitcnt vmcnt(0)" ::: "memory");

  const int i = lane >> 3, j = lane & 7;
  const short* q = &sq[wv][i * 192];
  const short* k = &sq[wv][j * 192 + 64];
  float s = 0.f;
#pragma unroll
  for (int c = 0; c < 8; ++c) {
    bh8 qa = *(const bh8*)&q[c * 8];
    bh8 ka = *(const bh8*)&k[c * 8];
#pragma unroll
    for (int e = 0; e < 8; ++e) s += bf2f(qa[e]) * bf2f(ka[e]);
  }
  s *= 0.125f;  // HEAD_DIM^-0.5

  float m = s;
  m = fmaxf(m, __shfl_xor(m, 1));
  m = fmaxf(m, __shfl_xor(m, 2));
  m = fmaxf(m, __shfl_xor(m, 4));
  float p = __expf(s - m);
  float sum = p;
  sum += __shfl_xor(sum, 1);
  sum += __shfl_xor(sum, 2);
  sum += __shfl_xor(sum, 4);
  const float a = p / sum;

  // output: lane covers head i, dims d = j*8 .. j*8+7
  float o[8] = {};
#pragma unroll
  for (int jj = 0; jj < 8; ++jj) {
    const float aj = __shfl(a, (lane & 56) | jj);
    bh8 va = *(const bh8*)&sq[wv][jj * 192 + 128 + j * 8];
#pragma unroll
    for (int e = 0; e < 8; ++e) o[e] += aj * bf2f(va[e]);
  }
  bh8 ov;
#pragma unroll
  for (int e = 0; e < 8; ++e) ov[e] = (short)f2bf(o[e]);
  *(bh8*)&AO[(size_t)t * 512 + i * 64 + j * 8] = ov;
}

// ---------- launch ----------
extern "C" void kernel_launch(void* const* d_in, const int* in_sizes, int n_in,
                              void* d_out, int out_size, void* d_ws,
                              size_t ws_size, hipStream_t stream) {
  const float* x = (const float*)d_in[0];
  // d_in[1] = _h (unused)
  const float* W_in = (const float*)d_in[2];
  const float* b_in = (const float*)d_in[3];
  const float* W_out = (const float*)d_in[4];
  const float* b_out = (const float*)d_in[5];
  float* out = (float*)d_out;

  // ws carve-up (bf16-bit buffers):
  //   Xbf  : 32768 x 512   (token-major X; later re-used per-chunk as AO)
  //   WinT : 1536 x 512
  //   WoutT:  512 x 512
  //   QKVc : (32768/NC) x 1536  (per-chunk QKV)
  // NC adapts to ws_size: peak = 34 MB + 96/NC MB (NC=1: 130 MB, 4: 58 MB).
  short* Xbf = (short*)d_ws;
  short* WinT = Xbf + (size_t)32768 * 512;
  short* WoutT = WinT + (size_t)1536 * 512;
  short* QKVc = WoutT + (size_t)512 * 512;

  const size_t fixed_bytes =
      ((size_t)32768 * 512 + (size_t)1536 * 512 + (size_t)512 * 512) * 2;
  int NC = 1;
  while (NC < 256 &&
         fixed_bytes + ((size_t)32768 / NC) * 1536 * 2 > ws_size)
    NC <<= 1;
  const int Mc = 32768 / NC;

  // X: (8,512,4096) -> (32768,512) bf16
  transpose_cvt<<<dim3(64, 8, 8), 256, 0, stream>>>(x, Xbf, 512, 4096);
  // W_in: (512,1536) -> (1536,512) bf16
  transpose_cvt<<<dim3(24, 8, 1), 256, 0, stream>>>(W_in, WinT, 512, 1536);
  // W_out: (512,512) -> (512,512)^T bf16
  transpose_cvt<<<dim3(8, 8, 1), 256, 0, stream>>>(W_out, WoutT, 512, 512);

  for (int c = 0; c < NC; ++c) {
    const int t0 = c * Mc;
    short* Ach = Xbf + (size_t)t0 * 512;  // chunk's X rows; later its AO rows
    // GEMM1: QKVc = Ach @ WinT^T + b_in   (M=Mc, N=1536, K=512)
    gemm_bt<1><<<dim3(12, Mc / 128), 256, 0, stream>>>(Ach, WinT, b_in, QKVc,
                                                       Mc, 1536, 512, 0);
    // attention over heads; AO written in-place over the chunk's X rows
    attn_kernel<<<dim3(Mc / 4), 256, 0, stream>>>(QKVc, Ach);
    // GEMM2: out(ch, tok0+n) = WoutT @ AO^T + b_out, scattered to (B,C,S) f32
    gemm_bt<2><<<dim3(Mc / 128, 4), 256, 0, stream>>>(WoutT, Ach, b_out, out,
                                                      512, Mc, 512, t0);
  }
}

// Round 4
// 253.876 us; speedup vs baseline: 1.0516x; 1.0075x over previous
//
#include <hip/hip_runtime.h>
#include <hip/hip_bf16.h>

// ---------- types / helpers ----------
typedef __attribute__((ext_vector_type(8))) short bh8;   // 8 bf16 bit patterns (4 VGPRs)
typedef __attribute__((ext_vector_type(4))) float fx4;

#define GLOAD16(g, l)                                                          \
  __builtin_amdgcn_global_load_lds(                                            \
      (const __attribute__((address_space(1))) void*)(g),                      \
      (__attribute__((address_space(3))) void*)(l), 16, 0, 0)

__device__ __forceinline__ unsigned short f2bf(float f) {
  unsigned int u = __float_as_uint(f);
  u += 0x7fffu + ((u >> 16) & 1u);     // RNE
  return (unsigned short)(u >> 16);
}
__device__ __forceinline__ float bf2f(short h) {
  return __uint_as_float(((unsigned int)(unsigned short)h) << 16);
}

// ---------- kernel 1: transpose + f32->bf16 convert ----------
// in: (Bn, R, C) f32 ; out: (Bn, C, R) bf16-bits
// Write phase packs 4 bf16 per lane (uint2, 8B) instead of scalar 2B stores.
__global__ __launch_bounds__(256) void transpose_cvt(
    const float* __restrict__ in, short* __restrict__ out, int R, int Ccols) {
  __shared__ float tile[64][65];
  const int b = blockIdx.z;
  const int c0 = blockIdx.x * 64;
  const int r0 = blockIdx.y * 64;
  const float* ip = in + (size_t)b * R * Ccols;
  short* op = out + (size_t)b * Ccols * R;
  const int tid = threadIdx.x;
  const int tx = tid & 63, ty = tid >> 6;
#pragma unroll
  for (int i = 0; i < 16; ++i) {
    int r = ty + i * 4;
    tile[tx][r] = ip[(size_t)(r0 + r) * Ccols + c0 + tx];
  }
  __syncthreads();
  const int cg = tid & 15;   // column group: 4 consecutive output cols (rows of in)
  const int rr = tid >> 4;   // 0..15
#pragma unroll
  for (int i = 0; i < 4; ++i) {
    const int cc = i * 16 + rr;  // local out-row (input col)
    const unsigned int lo = (unsigned int)f2bf(tile[cc][cg * 4 + 0]) |
                            ((unsigned int)f2bf(tile[cc][cg * 4 + 1]) << 16);
    const unsigned int hi = (unsigned int)f2bf(tile[cc][cg * 4 + 2]) |
                            ((unsigned int)f2bf(tile[cc][cg * 4 + 3]) << 16);
    uint2 v; v.x = lo; v.y = hi;
    *(uint2*)&op[(size_t)(c0 + cc) * R + r0 + cg * 4] = v;
  }
}

// ---------- GEMM: C = A(MxK) * Bt(NxK)^T, bf16 in, fp32 accum ----------
// 2-phase pipeline (dbuf LDS, prefetch-before-compute, one drain/iter).
// T1 XCD swizzle for L2 panel locality.
// T2-adapted LDS swizzle (rule #21: linear GLOAD dest + inverse-swizzled
// GLOBAL source koff + swizzled ds_read col): chunk' = chunk ^ ((row>>1)&3).
// Makes the 8-way-conflicted ds_read_b128 pattern conflict-free.
// MODE 1: out bf16 row-major MxN, bias indexed by col (b_in)
// MODE 2: rows are channels (M=512), cols are tokens (global tok = tok0+n);
//         out fp32 written to (B=8, C=512, S=4096), bias indexed by row (b_out)
template <int MODE>
__global__ __launch_bounds__(256) void gemm_bt(
    const short* __restrict__ A, const short* __restrict__ Bt,
    const float* __restrict__ bias, void* __restrict__ Cout,
    int M, int N, int K, int tok0) {
  __shared__ short As[2][128 * 32] __attribute__((aligned(16)));
  __shared__ short Bs[2][128 * 32] __attribute__((aligned(16)));
  const int tid = threadIdx.x;
  const int lane = tid & 63;
  const int wv = tid >> 6;
  const int wr = wv >> 1, wc = wv & 1;

  // ---- XCD-aware swizzle (bijective: nwg % 8 == 0 for all our grids) ----
  const int nbx = gridDim.x, nby = gridDim.y;
  const int nwg = nbx * nby;
  int h = blockIdx.y * nbx + blockIdx.x;
  int L = h;
  if ((nwg & 7) == 0) {
    const int q = nwg >> 3;
    L = (h & 7) * q + (h >> 3);
  }
  int bx, by;
  if (MODE == 1) {  // x-fastest: consecutive L share by (A panel)
    by = L / nbx;
    bx = L - by * nbx;
  } else {          // y-fastest: consecutive L share bx (B panel)
    bx = L / nby;
    by = L - bx * nby;
  }
  const int m0 = by * 128, n0 = bx * 128;

  const int lr = lane & 15;
  const int lk = (lane >> 4) * 8;
  const int rsw = ((lr >> 1) & 3) << 3;  // read-side swizzle, in shorts

  fx4 acc[4][4] = {};

  const int srow = tid >> 2;                              // 0..63
  const int skoff = (((tid & 3) ^ ((tid >> 3) & 3)) * 8); // pre-swizzled src k
  const size_t abase = (size_t)(m0 + srow) * K + skoff;
  const size_t bbase = (size_t)(n0 + srow) * K + skoff;
  const int ldoff = wv * 1024;         // per-wave LDS dest byte offset (linear)

  // prologue: stage K-tile 0 into buf 0
  {
    char* lA = (char*)As[0] + ldoff;
    char* lB = (char*)Bs[0] + ldoff;
    GLOAD16(A + abase, lA);
    GLOAD16(A + abase + (size_t)64 * K, lA + 4096);
    GLOAD16(Bt + bbase, lB);
    GLOAD16(Bt + bbase + (size_t)64 * K, lB + 4096);
  }
  __syncthreads();  // drains vmcnt(0) + barrier

  int cur = 0;
  for (int k0 = 0; k0 < K; k0 += 32) {
    // issue NEXT tile's loads first (latency hides under ds_read+MFMA below)
    if (k0 + 32 < K) {
      char* lA = (char*)As[cur ^ 1] + ldoff;
      char* lB = (char*)Bs[cur ^ 1] + ldoff;
      GLOAD16(A + abase + k0 + 32, lA);
      GLOAD16(A + abase + (size_t)64 * K + k0 + 32, lA + 4096);
      GLOAD16(Bt + bbase + k0 + 32, lB);
      GLOAD16(Bt + bbase + (size_t)64 * K + k0 + 32, lB + 4096);
    }

    bh8 af[4], bfm[4];
#pragma unroll
    for (int i = 0; i < 4; ++i) {
      af[i] = *(const bh8*)&As[cur][(wr * 64 + i * 16 + lr) * 32 + (lk ^ rsw)];
      bfm[i] = *(const bh8*)&Bs[cur][(wc * 64 + i * 16 + lr) * 32 + (lk ^ rsw)];
    }
#pragma unroll
    for (int i = 0; i < 4; ++i)
#pragma unroll
      for (int j = 0; j < 4; ++j)
        acc[i][j] = __builtin_amdgcn_mfma_f32_16x16x32_bf16(af[i], bfm[j],
                                                            acc[i][j], 0, 0, 0);

    __syncthreads();  // vmcnt(0): prefetched tile landed; lgkm drained; flip
    cur ^= 1;
  }

  if (MODE == 1) {
    short* C = (short*)Cout;
#pragma unroll
    for (int i = 0; i < 4; ++i) {
      const int gm = m0 + wr * 64 + i * 16 + (lane >> 4) * 4;
#pragma unroll
      for (int j = 0; j < 4; ++j) {
        const int gn = n0 + wc * 64 + j * 16 + lr;
        const float bv = bias[gn];
#pragma unroll
        for (int r = 0; r < 4; ++r)
          C[(size_t)(gm + r) * N + gn] = (short)f2bf(acc[i][j][r] + bv);
      }
    }
  } else {
    float* C = (float*)Cout;
#pragma unroll
    for (int i = 0; i < 4; ++i) {
      const int ch0 = m0 + wr * 64 + i * 16 + (lane >> 4) * 4;
#pragma unroll
      for (int j = 0; j < 4; ++j) {
        const int t = tok0 + n0 + wc * 64 + j * 16 + lr;
        const int bb = t >> 12, s = t & 4095;
#pragma unroll
        for (int r = 0; r < 4; ++r) {
          const int ch = ch0 + r;
          C[((size_t)(bb * 512 + ch)) * 4096 + s] = acc[i][j][r] + bias[ch];
        }
      }
    }
  }
}

// ---------- attention over heads axis: one wave per token ----------
// QKV: (Mc, 1536) bf16 ; per token, per head h: q=row[h*192..+64), k=+64, v=+128
// AO: (Mc, 512) bf16 (chunk-local rows, caller offsets the pointer)
__global__ __launch_bounds__(256) void attn_kernel(
    const short* __restrict__ QKV, short* __restrict__ AO) {
  __shared__ short sq[4][1536] __attribute__((aligned(16)));
  const int tid = threadIdx.x, lane = tid & 63, wv = tid >> 6;
  const int t = blockIdx.x * 4 + wv;

  {  // stage 1536 bf16 (3072 B) per wave: 3 x (64 lanes x 16 B)
    const short* g = QKV + (size_t)t * 1536 + lane * 8;
    char* l = (char*)&sq[wv][0];
    GLOAD16(g, l);
    GLOAD16(g + 512, l + 1024);
    GLOAD16(g + 1024, l + 2048);
  }
  asm volatile("s_waitcnt vmcnt(0)" ::: "memory");

  const int i = lane >> 3, j = lane & 7;
  const short* q = &sq[wv][i * 192];
  const short* k = &sq[wv][j * 192 + 64];
  float s = 0.f;
#pragma unroll
  for (int c = 0; c < 8; ++c) {
    bh8 qa = *(const bh8*)&q[c * 8];
    bh8 ka = *(const bh8*)&k[c * 8];
#pragma unroll
    for (int e = 0; e < 8; ++e) s += bf2f(qa[e]) * bf2f(ka[e]);
  }
  s *= 0.125f;  // HEAD_DIM^-0.5

  float m = s;
  m = fmaxf(m, __shfl_xor(m, 1));
  m = fmaxf(m, __shfl_xor(m, 2));
  m = fmaxf(m, __shfl_xor(m, 4));
  float p = __expf(s - m);
  float sum = p;
  sum += __shfl_xor(sum, 1);
  sum += __shfl_xor(sum, 2);
  sum += __shfl_xor(sum, 4);
  const float a = p / sum;

  // output: lane covers head i, dims d = j*8 .. j*8+7
  float o[8] = {};
#pragma unroll
  for (int jj = 0; jj < 8; ++jj) {
    const float aj = __shfl(a, (lane & 56) | jj);
    bh8 va = *(const bh8*)&sq[wv][jj * 192 + 128 + j * 8];
#pragma unroll
    for (int e = 0; e < 8; ++e) o[e] += aj * bf2f(va[e]);
  }
  bh8 ov;
#pragma unroll
  for (int e = 0; e < 8; ++e) ov[e] = (short)f2bf(o[e]);
  *(bh8*)&AO[(size_t)t * 512 + i * 64 + j * 8] = ov;
}

// ---------- launch ----------
extern "C" void kernel_launch(void* const* d_in, const int* in_sizes, int n_in,
                              void* d_out, int out_size, void* d_ws,
                              size_t ws_size, hipStream_t stream) {
  const float* x = (const float*)d_in[0];
  // d_in[1] = _h (unused)
  const float* W_in = (const float*)d_in[2];
  const float* b_in = (const float*)d_in[3];
  const float* W_out = (const float*)d_in[4];
  const float* b_out = (const float*)d_in[5];
  float* out = (float*)d_out;

  // ws carve-up (bf16-bit buffers):
  //   Xbf  : 32768 x 512   (token-major X; later re-used per-chunk as AO)
  //   WinT : 1536 x 512
  //   WoutT:  512 x 512
  //   QKVc : (32768/NC) x 1536  (per-chunk QKV)
  // NC adapts to ws_size: peak = 34 MB + 96/NC MB (NC=1: 130 MB, 4: 58 MB).
  short* Xbf = (short*)d_ws;
  short* WinT = Xbf + (size_t)32768 * 512;
  short* WoutT = WinT + (size_t)1536 * 512;
  short* QKVc = WoutT + (size_t)512 * 512;

  const size_t fixed_bytes =
      ((size_t)32768 * 512 + (size_t)1536 * 512 + (size_t)512 * 512) * 2;
  int NC = 1;
  while (NC < 256 &&
         fixed_bytes + ((size_t)32768 / NC) * 1536 * 2 > ws_size)
    NC <<= 1;
  const int Mc = 32768 / NC;

  // X: (8,512,4096) -> (32768,512) bf16
  transpose_cvt<<<dim3(64, 8, 8), 256, 0, stream>>>(x, Xbf, 512, 4096);
  // W_in: (512,1536) -> (1536,512) bf16
  transpose_cvt<<<dim3(24, 8, 1), 256, 0, stream>>>(W_in, WinT, 512, 1536);
  // W_out: (512,512) -> (512,512)^T bf16
  transpose_cvt<<<dim3(8, 8, 1), 256, 0, stream>>>(W_out, WoutT, 512, 512);

  for (int c = 0; c < NC; ++c) {
    const int t0 = c * Mc;
    short* Ach = Xbf + (size_t)t0 * 512;  // chunk's X rows; later its AO rows
    // GEMM1: QKVc = Ach @ WinT^T + b_in   (M=Mc, N=1536, K=512)
    gemm_bt<1><<<dim3(12, Mc / 128), 256, 0, stream>>>(Ach, WinT, b_in, QKVc,
                                                       Mc, 1536, 512, 0);
    // attention over heads; AO written in-place over the chunk's X rows
    attn_kernel<<<dim3(Mc / 4), 256, 0, stream>>>(QKVc, Ach);
    // GEMM2: out(ch, tok0+n) = WoutT @ AO^T + b_out, scattered to (B,C,S) f32
    gemm_bt<2><<<dim3(Mc / 128, 4), 256, 0, stream>>>(WoutT, Ach, b_out, out,
                                                      512, Mc, 512, t0);
  }
}

// Round 5
// 243.725 us; speedup vs baseline: 1.0954x; 1.0416x over previous
//
#include <hip/hip_runtime.h>
#include <hip/hip_bf16.h>

// ---------- types / helpers ----------
typedef __attribute__((ext_vector_type(8))) short bh8;   // 8 bf16 bit patterns (4 VGPRs)
typedef __attribute__((ext_vector_type(4))) float fx4;

#define GLOAD16(g, l)                                                          \
  __builtin_amdgcn_global_load_lds(                                            \
      (const __attribute__((address_space(1))) void*)(g),                      \
      (__attribute__((address_space(3))) void*)(l), 16, 0, 0)

__device__ __forceinline__ unsigned short f2bf(float f) {
  unsigned int u = __float_as_uint(f);
  u += 0x7fffu + ((u >> 16) & 1u);     // RNE
  return (unsigned short)(u >> 16);
}
__device__ __forceinline__ float bf2f(short h) {
  return __uint_as_float(((unsigned int)(unsigned short)h) << 16);
}

// ---------- kernel 1: transpose + f32->bf16 convert ----------
// in: (Bn, R, C) f32 ; out: (Bn, C, R) bf16-bits
__global__ __launch_bounds__(256) void transpose_cvt(
    const float* __restrict__ in, short* __restrict__ out, int R, int Ccols) {
  __shared__ float tile[64][65];
  const int b = blockIdx.z;
  const int c0 = blockIdx.x * 64;
  const int r0 = blockIdx.y * 64;
  const float* ip = in + (size_t)b * R * Ccols;
  short* op = out + (size_t)b * Ccols * R;
  const int tid = threadIdx.x;
  const int tx = tid & 63, ty = tid >> 6;
#pragma unroll
  for (int i = 0; i < 16; ++i) {
    int r = ty + i * 4;
    tile[tx][r] = ip[(size_t)(r0 + r) * Ccols + c0 + tx];
  }
  __syncthreads();
  const int cg = tid & 15;   // column group: 4 consecutive output cols
  const int rr = tid >> 4;   // 0..15
#pragma unroll
  for (int i = 0; i < 4; ++i) {
    const int cc = i * 16 + rr;  // local out-row (input col)
    const unsigned int lo = (unsigned int)f2bf(tile[cc][cg * 4 + 0]) |
                            ((unsigned int)f2bf(tile[cc][cg * 4 + 1]) << 16);
    const unsigned int hi = (unsigned int)f2bf(tile[cc][cg * 4 + 2]) |
                            ((unsigned int)f2bf(tile[cc][cg * 4 + 3]) << 16);
    uint2 v; v.x = lo; v.y = hi;
    *(uint2*)&op[(size_t)(c0 + cc) * R + r0 + cg * 4] = v;
  }
}

// ---------- GEMM: C = A(MxKC) * Bt(NxKC)^T, bf16 in, fp32 accum ----------
// T4 counted-vmcnt 3-slot LDS ring (prefetch distance 2 K-tiles, never
// vmcnt(0) in-loop), raw s_barrier (no __syncthreads drain), T1 XCD swizzle,
// conflict-free LDS chunk swizzle (rule #21: linear GLOAD dest +
// inverse-swizzled global src koff + swizzled ds_read col).
// Per-iter: vmcnt(4)[own tile-t landed] -> s_barrier[collective + slot free]
//           -> issue tile t+2 -> ds_read + 16 MFMA.
// MODE 1: out bf16 row-major MxN, bias indexed by col (b_in)
// MODE 2: rows are channels (M=512), cols are tokens (global tok = tok0+n);
//         out fp32 written to (B=8, C=512, S=4096), bias indexed by row (b_out)
template <int MODE, int KC>
__global__ __launch_bounds__(256) void gemm_bt(
    const short* __restrict__ A, const short* __restrict__ Bt,
    const float* __restrict__ bias, void* __restrict__ Cout,
    int M, int N, int tok0) {
  __shared__ short As[3][128 * 32] __attribute__((aligned(16)));
  __shared__ short Bs[3][128 * 32] __attribute__((aligned(16)));
  constexpr int NT = KC / 32;
  const int tid = threadIdx.x;
  const int lane = tid & 63;
  const int wv = tid >> 6;
  const int wr = wv >> 1, wc = wv & 1;

  // ---- XCD-aware swizzle (bijective: nwg % 8 == 0 for all our grids) ----
  const int nbx = gridDim.x, nby = gridDim.y;
  const int nwg = nbx * nby;
  int h = blockIdx.y * nbx + blockIdx.x;
  int L = h;
  if ((nwg & 7) == 0) {
    const int q = nwg >> 3;
    L = (h & 7) * q + (h >> 3);
  }
  int bx, by;
  if (MODE == 1) {  // x-fastest: consecutive L share by (A panel)
    by = L / nbx;
    bx = L - by * nbx;
  } else {          // y-fastest: consecutive L share bx (B panel)
    bx = L / nby;
    by = L - bx * nby;
  }
  const int m0 = by * 128, n0 = bx * 128;

  const int lr = lane & 15;
  const int lk = (lane >> 4) * 8;
  const int rsw = ((lr >> 1) & 3) << 3;  // read-side swizzle, in shorts

  fx4 acc[4][4] = {};

  const int srow = tid >> 2;                              // 0..63
  const int skoff = (((tid & 3) ^ ((tid >> 3) & 3)) * 8); // pre-swizzled src k
  const size_t abase = (size_t)(m0 + srow) * KC + skoff;
  const size_t bbase = (size_t)(n0 + srow) * KC + skoff;
  const int ldoff = wv * 1024;  // per-wave LDS dest byte offset (linear)

  // stage K-tile kt into ring slot
  auto STAGE = [&](int kt, int slot) {
    const size_t ko = (size_t)kt * 32;
    char* lA = (char*)As[slot] + ldoff;
    char* lB = (char*)Bs[slot] + ldoff;
    GLOAD16(A + abase + ko, lA);
    GLOAD16(A + abase + (size_t)64 * KC + ko, lA + 4096);
    GLOAD16(Bt + bbase + ko, lB);
    GLOAD16(Bt + bbase + (size_t)64 * KC + ko, lB + 4096);
  };

  // prologue: stage tiles 0,1 into slots 0,1 (8 VMEM instrs/wave in flight)
  STAGE(0, 0);
  STAGE(1, 1);

  for (int t = 0; t < NT; ++t) {
    __builtin_amdgcn_sched_barrier(0);
    if (t < NT - 1) {
      asm volatile("s_waitcnt vmcnt(4)" ::: "memory");  // own tile-t landed
    } else {
      asm volatile("s_waitcnt vmcnt(0)" ::: "memory");  // last tile drain
    }
    __builtin_amdgcn_s_barrier();   // collective: tile t in LDS; slot (t-1)%3
                                    // no longer read by any wave
    __builtin_amdgcn_sched_barrier(0);
    if (t + 2 < NT) STAGE(t + 2, (t + 2) % 3);  // lands >= issue: slot safe
    __builtin_amdgcn_sched_barrier(0);

    const int sl = t % 3;
    bh8 af[4], bfm[4];
#pragma unroll
    for (int i = 0; i < 4; ++i) {
      af[i] = *(const bh8*)&As[sl][(wr * 64 + i * 16 + lr) * 32 + (lk ^ rsw)];
      bfm[i] = *(const bh8*)&Bs[sl][(wc * 64 + i * 16 + lr) * 32 + (lk ^ rsw)];
    }
#pragma unroll
    for (int i = 0; i < 4; ++i)
#pragma unroll
      for (int j = 0; j < 4; ++j)
        acc[i][j] = __builtin_amdgcn_mfma_f32_16x16x32_bf16(af[i], bfm[j],
                                                            acc[i][j], 0, 0, 0);
  }

  if (MODE == 1) {
    short* C = (short*)Cout;
#pragma unroll
    for (int i = 0; i < 4; ++i) {
      const int gm = m0 + wr * 64 + i * 16 + (lane >> 4) * 4;
#pragma unroll
      for (int j = 0; j < 4; ++j) {
        const int gn = n0 + wc * 64 + j * 16 + lr;
        const float bv = bias[gn];
#pragma unroll
        for (int r = 0; r < 4; ++r)
          C[(size_t)(gm + r) * N + gn] = (short)f2bf(acc[i][j][r] + bv);
      }
    }
  } else {
    float* C = (float*)Cout;
#pragma unroll
    for (int i = 0; i < 4; ++i) {
      const int ch0 = m0 + wr * 64 + i * 16 + (lane >> 4) * 4;
#pragma unroll
      for (int j = 0; j < 4; ++j) {
        const int t = tok0 + n0 + wc * 64 + j * 16 + lr;
        const int bb = t >> 12, s = t & 4095;
#pragma unroll
        for (int r = 0; r < 4; ++r) {
          const int ch = ch0 + r;
          C[((size_t)(bb * 512 + ch)) * 4096 + s] = acc[i][j][r] + bias[ch];
        }
      }
    }
  }
}

// ---------- attention over heads axis: one wave per token ----------
// QKV: (Mc, 1536) bf16 ; per token, per head h: q=row[h*192..+64), k=+64, v=+128
// AO: (Mc, 512) bf16 (chunk-local rows, caller offsets the pointer)
__global__ __launch_bounds__(256) void attn_kernel(
    const short* __restrict__ QKV, short* __restrict__ AO) {
  __shared__ short sq[4][1536] __attribute__((aligned(16)));
  const int tid = threadIdx.x, lane = tid & 63, wv = tid >> 6;
  const int t = blockIdx.x * 4 + wv;

  {  // stage 1536 bf16 (3072 B) per wave: 3 x (64 lanes x 16 B)
    const short* g = QKV + (size_t)t * 1536 + lane * 8;
    char* l = (char*)&sq[wv][0];
    GLOAD16(g, l);
    GLOAD16(g + 512, l + 1024);
    GLOAD16(g + 1024, l + 2048);
  }
  asm volatile("s_waitcnt vmcnt(0)" ::: "memory");

  const int i = lane >> 3, j = lane & 7;
  const short* q = &sq[wv][i * 192];
  const short* k = &sq[wv][j * 192 + 64];
  float s = 0.f;
#pragma unroll
  for (int c = 0; c < 8; ++c) {
    bh8 qa = *(const bh8*)&q[c * 8];
    bh8 ka = *(const bh8*)&k[c * 8];
#pragma unroll
    for (int e = 0; e < 8; ++e) s += bf2f(qa[e]) * bf2f(ka[e]);
  }
  s *= 0.125f;  // HEAD_DIM^-0.5

  float m = s;
  m = fmaxf(m, __shfl_xor(m, 1));
  m = fmaxf(m, __shfl_xor(m, 2));
  m = fmaxf(m, __shfl_xor(m, 4));
  float p = __expf(s - m);
  float sum = p;
  sum += __shfl_xor(sum, 1);
  sum += __shfl_xor(sum, 2);
  sum += __shfl_xor(sum, 4);
  const float a = p / sum;

  // output: lane covers head i, dims d = j*8 .. j*8+7
  float o[8] = {};
#pragma unroll
  for (int jj = 0; jj < 8; ++jj) {
    const float aj = __shfl(a, (lane & 56) | jj);
    bh8 va = *(const bh8*)&sq[wv][jj * 192 + 128 + j * 8];
#pragma unroll
    for (int e = 0; e < 8; ++e) o[e] += aj * bf2f(va[e]);
  }
  bh8 ov;
#pragma unroll
  for (int e = 0; e < 8; ++e) ov[e] = (short)f2bf(o[e]);
  *(bh8*)&AO[(size_t)t * 512 + i * 64 + j * 8] = ov;
}

// ---------- launch ----------
extern "C" void kernel_launch(void* const* d_in, const int* in_sizes, int n_in,
                              void* d_out, int out_size, void* d_ws,
                              size_t ws_size, hipStream_t stream) {
  const float* x = (const float*)d_in[0];
  // d_in[1] = _h (unused)
  const float* W_in = (const float*)d_in[2];
  const float* b_in = (const float*)d_in[3];
  const float* W_out = (const float*)d_in[4];
  const float* b_out = (const float*)d_in[5];
  float* out = (float*)d_out;

  // ws carve-up (bf16-bit buffers):
  //   Xbf  : 32768 x 512   (token-major X; later re-used per-chunk as AO)
  //   WinT : 1536 x 512
  //   WoutT:  512 x 512
  //   QKVc : (32768/NC) x 1536  (per-chunk QKV)
  // NC adapts to ws_size: peak = 34 MB + 96/NC MB (NC=1: 130 MB, 4: 58 MB).
  short* Xbf = (short*)d_ws;
  short* WinT = Xbf + (size_t)32768 * 512;
  short* WoutT = WinT + (size_t)1536 * 512;
  short* QKVc = WoutT + (size_t)512 * 512;

  const size_t fixed_bytes =
      ((size_t)32768 * 512 + (size_t)1536 * 512 + (size_t)512 * 512) * 2;
  int NC = 1;
  while (NC < 256 &&
         fixed_bytes + ((size_t)32768 / NC) * 1536 * 2 > ws_size)
    NC <<= 1;
  const int Mc = 32768 / NC;

  // X: (8,512,4096) -> (32768,512) bf16
  transpose_cvt<<<dim3(64, 8, 8), 256, 0, stream>>>(x, Xbf, 512, 4096);
  // W_in: (512,1536) -> (1536,512) bf16
  transpose_cvt<<<dim3(24, 8, 1), 256, 0, stream>>>(W_in, WinT, 512, 1536);
  // W_out: (512,512) -> (512,512)^T bf16
  transpose_cvt<<<dim3(8, 8, 1), 256, 0, stream>>>(W_out, WoutT, 512, 512);

  for (int c = 0; c < NC; ++c) {
    const int t0 = c * Mc;
    short* Ach = Xbf + (size_t)t0 * 512;  // chunk's X rows; later its AO rows
    // GEMM1: QKVc = Ach @ WinT^T + b_in   (M=Mc, N=1536, K=512)
    gemm_bt<1, 512><<<dim3(12, Mc / 128), 256, 0, stream>>>(Ach, WinT, b_in,
                                                            QKVc, Mc, 1536, 0);
    // attention over heads; AO written in-place over the chunk's X rows
    attn_kernel<<<dim3(Mc / 4), 256, 0, stream>>>(QKVc, Ach);
    // GEMM2: out(ch, tok0+n) = WoutT @ AO^T + b_out, scattered to (B,C,S) f32
    gemm_bt<2, 512><<<dim3(Mc / 128, 4), 256, 0, stream>>>(WoutT, Ach, b_out,
                                                           out, 512, Mc, t0);
  }
}